// Round 1
// baseline (803.898 us; speedup 1.0000x reference)
//
#include <hip/hip_runtime.h>

// N=100000 nodes, E=1600000 edges, D=64.
#define D_FEAT 64
#define E_BLK 2048           // edges per hist/partition tile -> ntiles = 782
#define RB 128               // rows per bucket -> nb = ceil(N/128) = 782
#define MAXB 800             // max buckets (>= nb)
#define APAD 65              // LDS accumulator row stride (dwords), odd -> bank spread

// Edge packing: (local_row << 24) | col   (col < 2^24, local_row < 128)
// hist_t layout:     [bucket * ntiles + tile]
// base_local layout: [tile * MAXB + bucket]

__device__ inline unsigned short f2bf(float f) {
    unsigned u = __float_as_uint(f);
    u += 0x7FFFu + ((u >> 16) & 1u);   // RNE
    return (unsigned short)(u >> 16);
}
__device__ inline float bf_lo(unsigned u) { return __uint_as_float(u << 16); }
__device__ inline float bf_hi(unsigned u) { return __uint_as_float(u & 0xFFFF0000u); }

// ---------------- K1: per-tile bucket histogram (+ optional bf16 conv) -----
__global__ __launch_bounds__(256)
void hist_conv_kernel(const int* __restrict__ row, int* __restrict__ hist_t,
                      int n_edges, int nb, int ntiles,
                      const float* __restrict__ feat, unsigned short* __restrict__ feat_bf,
                      int n4) {
    int gb = blockIdx.x;
    int t = threadIdx.x;
    if (gb < ntiles) {
        __shared__ int h[MAXB];
        for (int i = t; i < MAXB; i += 256) h[i] = 0;
        __syncthreads();
        int e0 = gb * E_BLK, e1 = min(e0 + E_BLK, n_edges);
        for (int e = e0 + t; e < e1; e += 256)
            atomicAdd(&h[row[e] >> 7], 1);
        __syncthreads();
        for (int i = t; i < nb; i += 256)
            hist_t[(size_t)i * ntiles + gb] = h[i];
    } else {
        int i = (gb - ntiles) * 256 + t;
        if (i < n4) {
            float4 f = reinterpret_cast<const float4*>(feat)[i];
            ushort4 u;
            u.x = f2bf(f.x); u.y = f2bf(f.y); u.z = f2bf(f.z); u.w = f2bf(f.w);
            reinterpret_cast<ushort4*>(feat_bf)[i] = u;
        }
    }
}

// ---------------- K2: per-bucket scan over tiles -> bases + totals ---------
__global__ __launch_bounds__(256)
void bases_kernel(const int* __restrict__ hist_t, int* __restrict__ base_local,
                  int* __restrict__ bucket_total, int ntiles) {
    __shared__ int s[256];
    int b = blockIdx.x;
    int t = threadIdx.x;
    const int* hp = hist_t + (size_t)b * ntiles;
    int v[4];
    int sum = 0;
    #pragma unroll
    for (int k = 0; k < 4; ++k) {
        int j = t * 4 + k;
        v[k] = (j < ntiles) ? hp[j] : 0;
        sum += v[k];
    }
    s[t] = sum;
    __syncthreads();
    for (int o = 1; o < 256; o <<= 1) {
        int x = (t >= o) ? s[t - o] : 0;
        __syncthreads();
        s[t] += x;
        __syncthreads();
    }
    int run = s[t] - sum;
    if (t == 255) bucket_total[b] = s[255];
    #pragma unroll
    for (int k = 0; k < 4; ++k) {
        int j = t * 4 + k;
        if (j < ntiles) base_local[(size_t)j * MAXB + b] = run;
        run += v[k];
    }
}

// ---------------- K3: partition (in-block bucket_off scan, LDS cursors) ----
__global__ __launch_bounds__(256)
void partition_kernel(const int* __restrict__ row, const int* __restrict__ col,
                      const int* __restrict__ bucket_total,
                      const int* __restrict__ base_local,
                      int* __restrict__ binned, int n_edges, int nb) {
    __shared__ int cur[MAXB];
    __shared__ int s[256];
    int t = threadIdx.x;
    int gb = blockIdx.x;
    int v[4];
    int sum = 0;
    #pragma unroll
    for (int k = 0; k < 4; ++k) {
        int j = t * 4 + k;
        v[k] = (j < nb) ? bucket_total[j] : 0;
        sum += v[k];
    }
    s[t] = sum;
    __syncthreads();
    for (int o = 1; o < 256; o <<= 1) {
        int x = (t >= o) ? s[t - o] : 0;
        __syncthreads();
        s[t] += x;
        __syncthreads();
    }
    int run = s[t] - sum;
    #pragma unroll
    for (int k = 0; k < 4; ++k) {
        int j = t * 4 + k;
        if (j < nb) cur[j] = run;
        run += v[k];
    }
    __syncthreads();
    const int* bl = base_local + (size_t)gb * MAXB;
    for (int i = t; i < nb; i += 256) cur[i] += bl[i];
    __syncthreads();
    int e0 = gb * E_BLK, e1 = min(e0 + E_BLK, n_edges);
    for (int e = e0 + t; e < e1; e += 256) {
        int r = row[e];
        int pos = atomicAdd(&cur[r >> 7], 1);
        binned[pos] = ((r & (RB - 1)) << 24) | col[e];
    }
}

// ---------------- K4: block per 128-row bucket; LDS fp32 accumulation ------
// Consumes bucket-grouped (unsorted-within-bucket) edges directly; no CSR pass.
template<int BF>
__global__ __launch_bounds__(256)
void aggregate2_kernel(const float* __restrict__ feat,
                       const unsigned short* __restrict__ feat_bf,
                       const int* __restrict__ binned,
                       const int* __restrict__ bucket_total,
                       float* __restrict__ out, int n_nodes) {
    __shared__ float acc[RB * APAD];   // 128*65*4 = 33.3 KB, stride 65 spreads banks
    __shared__ int dcnt[RB];
    __shared__ int red[256];
    int b = blockIdx.x;
    int t = threadIdx.x;

    for (int j = t; j < RB * APAD; j += 256) acc[j] = 0.f;
    if (t < RB) dcnt[t] = 0;

    // start = prefix sum of bucket_total[0..b)
    int partial = 0;
    for (int j = t; j < b; j += 256) partial += bucket_total[j];
    red[t] = partial;
    __syncthreads();
    for (int o = 128; o > 0; o >>= 1) {
        if (t < o) red[t] += red[t + o];
        __syncthreads();
    }
    int start = red[0];
    int end = start + bucket_total[b];

    int g = t >> 3;        // edge slot within 32-edge group
    int s = t & 7;         // 16B slot within the feature row
    for (int e0 = start; e0 < end; e0 += 64) {
        int eA = e0 + g;
        int eB = eA + 32;
        int pkA = (eA < end) ? binned[eA] : -1;   // valid pk always >= 0 (lr < 128)
        int pkB = (eB < end) ? binned[eB] : -1;
        float fA[8], fB[8];
        if (pkA >= 0) {
            size_t c = (size_t)(pkA & 0xFFFFFF);
            if (BF) {
                uint4 d = *reinterpret_cast<const uint4*>(feat_bf + c * D_FEAT + s * 8);
                fA[0] = bf_lo(d.x); fA[1] = bf_hi(d.x);
                fA[2] = bf_lo(d.y); fA[3] = bf_hi(d.y);
                fA[4] = bf_lo(d.z); fA[5] = bf_hi(d.z);
                fA[6] = bf_lo(d.w); fA[7] = bf_hi(d.w);
            } else {
                float4 x0 = *reinterpret_cast<const float4*>(feat + c * D_FEAT + s * 8);
                float4 x1 = *reinterpret_cast<const float4*>(feat + c * D_FEAT + s * 8 + 4);
                fA[0] = x0.x; fA[1] = x0.y; fA[2] = x0.z; fA[3] = x0.w;
                fA[4] = x1.x; fA[5] = x1.y; fA[6] = x1.z; fA[7] = x1.w;
            }
        }
        if (pkB >= 0) {
            size_t c = (size_t)(pkB & 0xFFFFFF);
            if (BF) {
                uint4 d = *reinterpret_cast<const uint4*>(feat_bf + c * D_FEAT + s * 8);
                fB[0] = bf_lo(d.x); fB[1] = bf_hi(d.x);
                fB[2] = bf_lo(d.y); fB[3] = bf_hi(d.y);
                fB[4] = bf_lo(d.z); fB[5] = bf_hi(d.z);
                fB[6] = bf_lo(d.w); fB[7] = bf_hi(d.w);
            } else {
                float4 x0 = *reinterpret_cast<const float4*>(feat + c * D_FEAT + s * 8);
                float4 x1 = *reinterpret_cast<const float4*>(feat + c * D_FEAT + s * 8 + 4);
                fB[0] = x0.x; fB[1] = x0.y; fB[2] = x0.z; fB[3] = x0.w;
                fB[4] = x1.x; fB[5] = x1.y; fB[6] = x1.z; fB[7] = x1.w;
            }
        }
        if (pkA >= 0) {
            int lr = ((unsigned)pkA) >> 24;
            float* a = acc + lr * APAD + s * 8;
            #pragma unroll
            for (int k = 0; k < 8; ++k) atomicAdd(a + k, fA[k]);
            if (s == 0) atomicAdd(&dcnt[lr], 1);
        }
        if (pkB >= 0) {
            int lr = ((unsigned)pkB) >> 24;
            float* a = acc + lr * APAD + s * 8;
            #pragma unroll
            for (int k = 0; k < 8; ++k) atomicAdd(a + k, fB[k]);
            if (s == 0) atomicAdd(&dcnt[lr], 1);
        }
    }
    __syncthreads();

    // epilogue: out[r] = feat[r] + acc[r]/max(deg,1); fully coalesced
    int r0 = b * RB;
    for (int j = t; j < RB * (D_FEAT / 4); j += 256) {
        int lr = j >> 4;
        int r = r0 + lr;
        if (r >= n_nodes) break;   // rows increase with j for fixed t
        int f = (j & 15) * 4;
        float inv = 1.0f / fmaxf((float)dcnt[lr], 1.0f);
        const float* a = acc + lr * APAD + f;
        size_t off = (size_t)r * D_FEAT + f;
        float4 fv = *reinterpret_cast<const float4*>(feat + off);
        float4 o;
        o.x = fv.x + a[0] * inv;
        o.y = fv.y + a[1] * inv;
        o.z = fv.z + a[2] * inv;
        o.w = fv.w + a[3] * inv;
        *reinterpret_cast<float4*>(out + off) = o;
    }
}

extern "C" void kernel_launch(void* const* d_in, const int* in_sizes, int n_in,
                              void* d_out, int out_size, void* d_ws, size_t ws_size,
                              hipStream_t stream) {
    const float* feat = (const float*)d_in[0];
    const int* row = (const int*)d_in[1];
    const int* col = (const int*)d_in[2];
    float* out = (float*)d_out;

    const int n_nodes = in_sizes[0] / D_FEAT;
    const int n_edges = in_sizes[1];
    const int nb = (n_nodes + RB - 1) / RB;               // 782
    const int ntiles = (n_edges + E_BLK - 1) / E_BLK;     // 782
    const int n4 = n_nodes * D_FEAT / 4;                  // 1.6M float4s

    size_t bf_bytes     = (size_t)n_nodes * D_FEAT * 2;   // 12.8 MB
    size_t binned_bytes = (size_t)n_edges * 4;            // 6.4 MB
    size_t hist_bytes   = (size_t)nb * ntiles * 4;        // 2.45 MB
    size_t base_bytes   = (size_t)ntiles * MAXB * 4;      // 2.5 MB
    size_t bt_bytes     = (size_t)nb * 4;

    size_t lean_need = binned_bytes + hist_bytes + base_bytes + bt_bytes + 256;
    size_t fat_need  = lean_need + ((bf_bytes + 63) & ~(size_t)63) + 64;
    bool fat = (ws_size >= fat_need);

    char* ws = (char*)d_ws;
    size_t p = 0;
    unsigned short* feat_bf = nullptr;
    if (fat) { feat_bf = (unsigned short*)(ws + p); p += (bf_bytes + 63) & ~(size_t)63; }
    int* binned       = (int*)(ws + p); p += binned_bytes;
    int* hist_t       = (int*)(ws + p); p += hist_bytes;
    int* base_local   = (int*)(ws + p); p += base_bytes;
    int* bucket_total = (int*)(ws + p);

    {
        int conv_blocks = fat ? (n4 + 255) / 256 : 0;
        hist_conv_kernel<<<ntiles + conv_blocks, 256, 0, stream>>>(
            row, hist_t, n_edges, nb, ntiles, feat, feat_bf, n4);
    }
    bases_kernel<<<nb, 256, 0, stream>>>(hist_t, base_local, bucket_total, ntiles);
    partition_kernel<<<ntiles, 256, 0, stream>>>(row, col, bucket_total, base_local,
                                                 binned, n_edges, nb);
    if (fat) {
        aggregate2_kernel<1><<<nb, 256, 0, stream>>>(feat, feat_bf, binned, bucket_total,
                                                     out, n_nodes);
    } else {
        aggregate2_kernel<0><<<nb, 256, 0, stream>>>(feat, nullptr, binned, bucket_total,
                                                     out, n_nodes);
    }
}

// Round 2
// 231.539 us; speedup vs baseline: 3.4720x; 3.4720x over previous
//
#include <hip/hip_runtime.h>

// N=100000 nodes, E=1600000 edges, D=64.
// Pipeline: memset(cursors) -> bin_conv (global-atomic bucket binning + bf16 conv)
//           -> aggregate3 (per-bucket LDS counting sort + register accumulation).
#define D_FEAT 64
#define RB 64                 // rows per bucket -> nb = ceil(N/64) = 1563
#define RBITS 6
#define CAP 2048              // slab capacity/bucket; mean deg*RB = 1024, sd ~32 -> +32 sigma
#define OVCAP 131072          // overflow side-list capacity (never hit for random input)
#define E_BLK 2048            // edges per bin tile -> 782 bin blocks
#define CURSTRIDE 16          // one cursor per 64B line (atomic contention spread)

__device__ inline unsigned short f2bf(float f) {
    unsigned u = __float_as_uint(f);
    u += 0x7FFFu + ((u >> 16) & 1u);   // RNE
    return (unsigned short)(u >> 16);
}
__device__ inline float bf_lo(unsigned u) { return __uint_as_float(u << 16); }
__device__ inline float bf_hi(unsigned u) { return __uint_as_float(u & 0xFFFF0000u); }

// ---------------- K1: direct binning via global int atomics (+ bf16 conv) --
__global__ __launch_bounds__(256)
void bin_conv_kernel(const int* __restrict__ row, const int* __restrict__ col,
                     int* __restrict__ cursor,        // nb*CURSTRIDE, pre-zeroed
                     int* __restrict__ ovfcnt,        // 1 int, pre-zeroed
                     int* __restrict__ slab,          // [nb][CAP]
                     int2* __restrict__ ovf,          // [OVCAP]
                     int n_edges, int ebt,
                     const float* __restrict__ feat, unsigned short* __restrict__ feat_bf,
                     int n4) {
    int gb = blockIdx.x;
    int t = threadIdx.x;
    if (gb < ebt) {
        int e0 = gb * E_BLK, e1 = min(e0 + E_BLK, n_edges);
        for (int e = e0 + t; e < e1; e += 256) {
            int r = row[e], c = col[e];
            int b = r >> RBITS;
            int pos = atomicAdd(&cursor[b * CURSTRIDE], 1);
            if (pos < CAP) {
                slab[(size_t)b * CAP + pos] = ((r & (RB - 1)) << 24) | c;
            } else {
                int op = atomicAdd(ovfcnt, 1);
                if (op < OVCAP) ovf[op] = make_int2(r, c);
            }
        }
    } else {
        int i = (gb - ebt) * 256 + t;
        if (i < n4) {
            float4 f = reinterpret_cast<const float4*>(feat)[i];
            ushort4 u;
            u.x = f2bf(f.x); u.y = f2bf(f.y); u.z = f2bf(f.z); u.w = f2bf(f.w);
            reinterpret_cast<ushort4*>(feat_bf)[i] = u;
        }
    }
}

// ---------------- K2: per-bucket LDS counting sort + register aggregation --
// Block = 64-row bucket. Int LDS atomics only (native ds_add_u32); feature
// accumulation stays in registers, flushed once/row to wave-owned LDS fp32.
template<int BF>
__global__ __launch_bounds__(256, 6)
void aggregate3_kernel(const float* __restrict__ feat,
                       const unsigned short* __restrict__ feat_bf,
                       const int* __restrict__ slab,
                       const int* __restrict__ cursor,
                       const int* __restrict__ ovfcnt,
                       const int2* __restrict__ ovf,
                       const int* __restrict__ row, const int* __restrict__ col,
                       float* __restrict__ out, int n_nodes, int n_edges) {
    __shared__ int scol[CAP];                 // 8 KB sorted col indices
    __shared__ float accs[RB * D_FEAT];       // 16 KB fp32 row accumulators
    __shared__ int cnt[RB], csum[RB], cur[RB], ddeg[RB];

    int b = blockIdx.x;
    int t = threadIdx.x;
    int w = t >> 6, lane = t & 63;
    int q = lane >> 3, sub = lane & 7;

    for (int j = t; j < RB * D_FEAT; j += 256) accs[j] = 0.f;
    if (t < RB) { cnt[t] = 0; ddeg[t] = 0; }
    __syncthreads();

    int total = cursor[b * CURSTRIDE];
    int oc = *ovfcnt;
    bool rescan = (total > CAP) && (oc > OVCAP);   // some overflow entries dropped

    if (!rescan) {
        int nslab = min(total, CAP);
        // load slab chunk into registers + LDS histogram (int atomics)
        int pk[CAP / 256];
        #pragma unroll
        for (int k = 0; k < CAP / 256; ++k) {
            int idx = t + k * 256;
            pk[k] = (idx < nslab) ? slab[(size_t)b * CAP + idx] : -1;
            if (pk[k] >= 0) atomicAdd(&cnt[((unsigned)pk[k]) >> 24], 1);
        }
        __syncthreads();
        // inclusive scan of cnt -> csum (Hillis-Steele over 64)
        if (t < RB) csum[t] = cnt[t];
        __syncthreads();
        for (int o = 1; o < RB; o <<= 1) {
            int v = (t < RB && t >= o) ? csum[t - o] : 0;
            __syncthreads();
            if (t < RB) csum[t] += v;
            __syncthreads();
        }
        if (t < RB) { cur[t] = csum[t] - cnt[t]; ddeg[t] += cnt[t]; }
        __syncthreads();
        // scatter cols into row-grouped order
        #pragma unroll
        for (int k = 0; k < CAP / 256; ++k) {
            if (pk[k] >= 0) {
                int lr = ((unsigned)pk[k]) >> 24;
                int pos = atomicAdd(&cur[lr], 1);
                scol[pos] = pk[k] & 0xFFFFFF;
            }
        }
        __syncthreads();
        // per-wave register accumulation: wave w owns rows [w*16, w*16+16)
        for (int i = 0; i < RB / 4; ++i) {
            int lr = w * (RB / 4) + i;
            int cr = cnt[lr];
            if (cr == 0) continue;
            int s0 = csum[lr] - cr;
            float a0[8], a1[8];
            #pragma unroll
            for (int k = 0; k < 8; ++k) { a0[k] = 0.f; a1[k] = 0.f; }
            for (int base = 0; base < cr; base += 16) {
                int j0 = base + q;
                int j1 = base + 8 + q;
                int c0 = (j0 < cr) ? scol[s0 + j0] : -1;   // LDS broadcast in q-group
                int c1 = (j1 < cr) ? scol[s0 + j1] : -1;
                if (c0 >= 0) {
                    if (BF) {
                        uint4 d = *reinterpret_cast<const uint4*>(
                            feat_bf + (size_t)c0 * D_FEAT + sub * 8);
                        a0[0] += bf_lo(d.x); a0[1] += bf_hi(d.x);
                        a0[2] += bf_lo(d.y); a0[3] += bf_hi(d.y);
                        a0[4] += bf_lo(d.z); a0[5] += bf_hi(d.z);
                        a0[6] += bf_lo(d.w); a0[7] += bf_hi(d.w);
                    } else {
                        float4 x0 = *reinterpret_cast<const float4*>(feat + (size_t)c0 * D_FEAT + sub * 8);
                        float4 x1 = *reinterpret_cast<const float4*>(feat + (size_t)c0 * D_FEAT + sub * 8 + 4);
                        a0[0] += x0.x; a0[1] += x0.y; a0[2] += x0.z; a0[3] += x0.w;
                        a0[4] += x1.x; a0[5] += x1.y; a0[6] += x1.z; a0[7] += x1.w;
                    }
                }
                if (c1 >= 0) {
                    if (BF) {
                        uint4 d = *reinterpret_cast<const uint4*>(
                            feat_bf + (size_t)c1 * D_FEAT + sub * 8);
                        a1[0] += bf_lo(d.x); a1[1] += bf_hi(d.x);
                        a1[2] += bf_lo(d.y); a1[3] += bf_hi(d.y);
                        a1[4] += bf_lo(d.z); a1[5] += bf_hi(d.z);
                        a1[6] += bf_lo(d.w); a1[7] += bf_hi(d.w);
                    } else {
                        float4 x0 = *reinterpret_cast<const float4*>(feat + (size_t)c1 * D_FEAT + sub * 8);
                        float4 x1 = *reinterpret_cast<const float4*>(feat + (size_t)c1 * D_FEAT + sub * 8 + 4);
                        a1[0] += x0.x; a1[1] += x0.y; a1[2] += x0.z; a1[3] += x0.w;
                        a1[4] += x1.x; a1[5] += x1.y; a1[6] += x1.z; a1[7] += x1.w;
                    }
                }
            }
            #pragma unroll
            for (int k = 0; k < 8; ++k) a0[k] += a1[k];
            #pragma unroll
            for (int k = 0; k < 8; ++k) {
                a0[k] += __shfl_xor(a0[k], 8, 64);
                a0[k] += __shfl_xor(a0[k], 16, 64);
                a0[k] += __shfl_xor(a0[k], 32, 64);
            }
            if (q == 0) {
                float* ap = accs + lr * D_FEAT + sub * 8;
                #pragma unroll
                for (int k = 0; k < 8; ++k) ap[k] += a0[k];
            }
        }
        // overflow side-list (block-uniform condition; ~never taken)
        if (total > CAP) {
            __syncthreads();
            if (w == 0) {
                int noc = min(oc, OVCAP);
                for (int o0 = 0; o0 < noc; o0 += 64) {
                    int oi = o0 + lane;
                    int2 rc = (oi < noc) ? ovf[oi] : make_int2(-1, 0);
                    bool match = (rc.x >= 0) && ((rc.x >> RBITS) == b);
                    unsigned long long mask = __ballot(match);
                    while (mask) {
                        int l = __ffsll(mask) - 1;
                        int rr = __shfl(rc.x, l, 64);
                        int cc = __shfl(rc.y, l, 64);
                        int lr = rr & (RB - 1);
                        if (lane < 8) {
                            float fv[8];
                            if (BF) {
                                uint4 d = *reinterpret_cast<const uint4*>(
                                    feat_bf + (size_t)cc * D_FEAT + lane * 8);
                                fv[0] = bf_lo(d.x); fv[1] = bf_hi(d.x);
                                fv[2] = bf_lo(d.y); fv[3] = bf_hi(d.y);
                                fv[4] = bf_lo(d.z); fv[5] = bf_hi(d.z);
                                fv[6] = bf_lo(d.w); fv[7] = bf_hi(d.w);
                            } else {
                                float4 x0 = *reinterpret_cast<const float4*>(feat + (size_t)cc * D_FEAT + lane * 8);
                                float4 x1 = *reinterpret_cast<const float4*>(feat + (size_t)cc * D_FEAT + lane * 8 + 4);
                                fv[0] = x0.x; fv[1] = x0.y; fv[2] = x0.z; fv[3] = x0.w;
                                fv[4] = x1.x; fv[5] = x1.y; fv[6] = x1.z; fv[7] = x1.w;
                            }
                            float* ap = accs + lr * D_FEAT + lane * 8;
                            #pragma unroll
                            for (int k = 0; k < 8; ++k) ap[k] += fv[k];
                        }
                        if (lane == 0) ddeg[lr] += 1;
                        mask &= mask - 1;
                    }
                }
            }
        }
    } else {
        // correctness-only fallback: wave 0 rescans the raw edge list
        if (w == 0) {
            for (int e0 = 0; e0 < n_edges; e0 += 64) {
                int e = e0 + lane;
                int rr = (e < n_edges) ? row[e] : -1;
                int cc = (e < n_edges) ? col[e] : 0;
                bool match = (rr >= 0) && ((rr >> RBITS) == b);
                unsigned long long mask = __ballot(match);
                while (mask) {
                    int l = __ffsll(mask) - 1;
                    int r2 = __shfl(rr, l, 64);
                    int c2 = __shfl(cc, l, 64);
                    int lr = r2 & (RB - 1);
                    if (lane < 8) {
                        float fv[8];
                        if (BF) {
                            uint4 d = *reinterpret_cast<const uint4*>(
                                feat_bf + (size_t)c2 * D_FEAT + lane * 8);
                            fv[0] = bf_lo(d.x); fv[1] = bf_hi(d.x);
                            fv[2] = bf_lo(d.y); fv[3] = bf_hi(d.y);
                            fv[4] = bf_lo(d.z); fv[5] = bf_hi(d.z);
                            fv[6] = bf_lo(d.w); fv[7] = bf_hi(d.w);
                        } else {
                            float4 x0 = *reinterpret_cast<const float4*>(feat + (size_t)c2 * D_FEAT + lane * 8);
                            float4 x1 = *reinterpret_cast<const float4*>(feat + (size_t)c2 * D_FEAT + lane * 8 + 4);
                            fv[0] = x0.x; fv[1] = x0.y; fv[2] = x0.z; fv[3] = x0.w;
                            fv[4] = x1.x; fv[5] = x1.y; fv[6] = x1.z; fv[7] = x1.w;
                        }
                        float* ap = accs + lr * D_FEAT + lane * 8;
                        #pragma unroll
                        for (int k = 0; k < 8; ++k) ap[k] += fv[k];
                    }
                    if (lane == 0) ddeg[lr] += 1;
                    mask &= mask - 1;
                }
            }
        }
    }
    __syncthreads();

    // epilogue: out[r] = feat[r] + acc[r]/max(deg,1); fully coalesced
    int r0 = b * RB;
    for (int j = t; j < RB * (D_FEAT / 4); j += 256) {
        int lr = j >> 4;
        int r = r0 + lr;
        if (r >= n_nodes) break;   // rows increase with j for fixed t
        int f = (j & 15) * 4;
        float inv = 1.0f / fmaxf((float)ddeg[lr], 1.0f);
        const float* ap = accs + lr * D_FEAT + f;
        size_t off = (size_t)r * D_FEAT + f;
        float4 fv = *reinterpret_cast<const float4*>(feat + off);
        float4 o;
        o.x = fv.x + ap[0] * inv;
        o.y = fv.y + ap[1] * inv;
        o.z = fv.z + ap[2] * inv;
        o.w = fv.w + ap[3] * inv;
        *reinterpret_cast<float4*>(out + off) = o;
    }
}

extern "C" void kernel_launch(void* const* d_in, const int* in_sizes, int n_in,
                              void* d_out, int out_size, void* d_ws, size_t ws_size,
                              hipStream_t stream) {
    const float* feat = (const float*)d_in[0];
    const int* row = (const int*)d_in[1];
    const int* col = (const int*)d_in[2];
    float* out = (float*)d_out;

    const int n_nodes = in_sizes[0] / D_FEAT;
    const int n_edges = in_sizes[1];
    const int nb = (n_nodes + RB - 1) / RB;               // 1563
    const int ebt = (n_edges + E_BLK - 1) / E_BLK;        // 782
    const int n4 = n_nodes * D_FEAT / 4;                  // 1.6M float4s

    size_t slab_bytes = (size_t)nb * CAP * 4;             // 12.8 MB
    size_t cur_bytes  = ((size_t)nb * CURSTRIDE + 16) * 4; // ~100 KB (incl ovfcnt)
    size_t ovf_bytes  = (size_t)OVCAP * 8;                // 1 MB
    size_t bf_bytes   = (size_t)n_nodes * D_FEAT * 2;     // 12.8 MB

    size_t lean_need = slab_bytes + cur_bytes + ovf_bytes + 256;
    size_t fat_need  = lean_need + ((bf_bytes + 63) & ~(size_t)63);
    bool fat = (ws_size >= fat_need);

    char* ws = (char*)d_ws;
    size_t p = 0;
    int* slab   = (int*)(ws + p); p += slab_bytes;
    int* cursor = (int*)(ws + p); p += cur_bytes;
    int2* ovf   = (int2*)(ws + p); p += ovf_bytes;
    p = (p + 63) & ~(size_t)63;
    unsigned short* feat_bf = nullptr;
    if (fat) { feat_bf = (unsigned short*)(ws + p); }
    int* ovfcnt = cursor + (size_t)nb * CURSTRIDE;

    // zero cursors + overflow count (one small DMA dispatch)
    hipMemsetAsync(cursor, 0, ((size_t)nb * CURSTRIDE + 1) * 4, stream);

    {
        int conv_blocks = fat ? (n4 + 255) / 256 : 0;
        bin_conv_kernel<<<ebt + conv_blocks, 256, 0, stream>>>(
            row, col, cursor, ovfcnt, slab, ovf, n_edges, ebt,
            feat, feat_bf, fat ? n4 : 0);
    }
    if (fat) {
        aggregate3_kernel<1><<<nb, 256, 0, stream>>>(
            feat, feat_bf, slab, cursor, ovfcnt, ovf, row, col, out, n_nodes, n_edges);
    } else {
        aggregate3_kernel<0><<<nb, 256, 0, stream>>>(
            feat, nullptr, slab, cursor, ovfcnt, ovf, row, col, out, n_nodes, n_edges);
    }
}

// Round 4
// 185.138 us; speedup vs baseline: 4.3421x; 1.2506x over previous
//
#include <hip/hip_runtime.h>

// N=100000 nodes, E=1600000 edges, D=64.
// Pipeline: zero(cursors) -> part_conv (tile-histogram + run-reserved coalesced
// binning into 256-row coarse buckets, + bf16 conv) -> aggregate4 (per-64-row
// quarter: LDS counting sort + register gather/accumulate).
#define D_FEAT 64
#define RB 64                 // rows per aggregate block (quarter of coarse bucket)
#define CB 256                // rows per coarse bucket -> nb2 = ceil(N/256) = 391
#define NBMAX 512             // max coarse buckets
#define CAP2 4608             // slab capacity / coarse bucket (mean 4096, sd 64 -> +8 sigma)
#define SCAP 1536             // scol capacity / 64-row quarter (mean 1024, sd 32 -> +16 sigma)
#define OVCAP 65536           // overflow side list (never hit for random input)
#define E_BLK 8192            // edges per binning tile -> 196 tiles (runs ~21 edges = 84B)
#define CURSTRIDE 16          // one global cursor per 64B line

__device__ inline unsigned short f2bf(float f) {
    unsigned u = __float_as_uint(f);
    u += 0x7FFFu + ((u >> 16) & 1u);   // RNE
    return (unsigned short)(u >> 16);
}
__device__ inline float bf_lo(unsigned u) { return __uint_as_float(u << 16); }
__device__ inline float bf_hi(unsigned u) { return __uint_as_float(u & 0xFFFF0000u); }

// ---------------- K0: zero the global cursors + overflow count -------------
__global__ __launch_bounds__(256)
void zero_kernel(int* __restrict__ p, int n) {
    for (int i = blockIdx.x * 256 + threadIdx.x; i < n; i += gridDim.x * 256) p[i] = 0;
}

// ---------------- K1: run-reserved coalesced binning (+ bf16 conv) ---------
// Per 8192-edge tile: LDS histogram over 391 coarse buckets, ONE global
// atomicAdd per (tile,bucket) reserves a contiguous run, edges stream into
// their run via LDS cursors. Runs avg 21 edges -> line-granular writes.
__global__ __launch_bounds__(256)
void part_conv_kernel(const int* __restrict__ row, const int* __restrict__ col,
                      int* __restrict__ gcur,       // nb2*CURSTRIDE (+ovfcnt), pre-zeroed
                      int* __restrict__ slab,       // [nb2][CAP2]
                      int2* __restrict__ ovf,       // [OVCAP]
                      int n_edges, int ebt, int nb2,
                      const float* __restrict__ feat, unsigned short* __restrict__ feat_bf,
                      int n4) {
    int gb = blockIdx.x;
    int t = threadIdx.x;
    if (gb < ebt) {
        __shared__ int hist[NBMAX];
        __shared__ int cur[NBMAX];
        for (int i = t; i < nb2; i += 256) hist[i] = 0;
        __syncthreads();
        int e0 = gb * E_BLK, e1 = min(e0 + E_BLK, n_edges);
        for (int e = e0 + t; e < e1; e += 256)
            atomicAdd(&hist[row[e] >> 8], 1);
        __syncthreads();
        int* ovfcnt = gcur + (size_t)nb2 * CURSTRIDE;
        for (int i = t; i < nb2; i += 256) {
            int c = hist[i];
            cur[i] = (c > 0) ? atomicAdd(&gcur[i * CURSTRIDE], c) : 0;
        }
        __syncthreads();
        for (int e = e0 + t; e < e1; e += 256) {
            int r = row[e], c = col[e];
            int b = r >> 8;
            int pos = atomicAdd(&cur[b], 1);      // LDS atomic; base is global-reserved
            if (pos < CAP2) {
                slab[(size_t)b * CAP2 + pos] = ((r & 255) << 17) | c;   // col < 2^17
            } else {
                int op = atomicAdd(ovfcnt, 1);
                if (op < OVCAP) ovf[op] = make_int2(r, c);
            }
        }
    } else {
        int i = (gb - ebt) * 256 + t;
        if (i < n4) {
            float4 f = reinterpret_cast<const float4*>(feat)[i];
            ushort4 u;
            u.x = f2bf(f.x); u.y = f2bf(f.y); u.z = f2bf(f.z); u.w = f2bf(f.w);
            reinterpret_cast<ushort4*>(feat_bf)[i] = u;
        }
    }
}

// ---------------- K2: per-quarter LDS counting sort + register gather ------
// Block blk owns rows [blk*64, blk*64+64) = quarter (blk&3) of coarse bucket
// (blk>>2). Scans the coarse slab segment twice (L2-hot), sorts its rows'
// cols into scol, then register-accumulates 16 rows per wave.
template<int BF>
__global__ __launch_bounds__(256, 6)
void aggregate4_kernel(const float* __restrict__ feat,
                       const unsigned short* __restrict__ feat_bf,
                       const int* __restrict__ slab,
                       const int* __restrict__ gcur,
                       const int2* __restrict__ ovf,
                       const int* __restrict__ row, const int* __restrict__ col,
                       float* __restrict__ out, int n_nodes, int n_edges, int nb2) {
    __shared__ int scol[SCAP];                // 6 KB
    __shared__ float accs[RB * D_FEAT];       // 16 KB
    __shared__ int cnt[RB], csum[RB], cur[RB], ddeg[RB];

    int blk = blockIdx.x;
    int B = blk >> 2;          // coarse bucket
    int q = blk & 3;           // 64-row quarter
    int t = threadIdx.x;
    int w = t >> 6, lane = t & 63;
    int qg = lane >> 3, sub = lane & 7;

    for (int j = t; j < RB * D_FEAT; j += 256) accs[j] = 0.f;
    if (t < RB) { cnt[t] = 0; ddeg[t] = 0; }
    __syncthreads();

    int total = gcur[B * CURSTRIDE];
    int ns = min(total, CAP2);
    int oc = gcur[(size_t)nb2 * CURSTRIDE];
    const int* sp = slab + (size_t)B * CAP2;

    bool fb = (total > CAP2) && (oc > OVCAP);  // dropped edges -> raw rescan
    if (!fb) {
        // pass 1: histogram my quarter's rows
        for (int i = t; i < ns; i += 256) {
            int pk = sp[i];
            int lr8 = ((unsigned)pk) >> 17;
            if ((lr8 >> 6) == q) atomicAdd(&cnt[lr8 & 63], 1);
        }
        __syncthreads();
        if (t < RB) csum[t] = cnt[t];
        __syncthreads();
        for (int o = 1; o < RB; o <<= 1) {
            int v = (t < RB && t >= o) ? csum[t - o] : 0;
            __syncthreads();
            if (t < RB) csum[t] += v;
            __syncthreads();
        }
        fb = (csum[RB - 1] > SCAP);            // uniform (post-sync LDS read)
    }

    if (!fb) {
        if (t < RB) { cur[t] = csum[t] - cnt[t]; ddeg[t] = cnt[t]; }
        __syncthreads();
        // pass 2: scatter cols into row-grouped scol
        for (int i = t; i < ns; i += 256) {
            int pk = sp[i];
            int lr8 = ((unsigned)pk) >> 17;
            if ((lr8 >> 6) == q) {
                int pos = atomicAdd(&cur[lr8 & 63], 1);
                scol[pos] = pk & 0x1FFFF;
            }
        }
        __syncthreads();
        // register accumulation: wave w owns rows [w*16, w*16+16)
        for (int i = 0; i < RB / 4; ++i) {
            int lr = w * (RB / 4) + i;
            int cr = cnt[lr];
            if (cr == 0) continue;
            int s0 = csum[lr] - cr;
            float a0[8], a1[8];
            #pragma unroll
            for (int k = 0; k < 8; ++k) { a0[k] = 0.f; a1[k] = 0.f; }
            for (int base = 0; base < cr; base += 16) {
                int j0 = base + qg;
                int j1 = base + 8 + qg;
                int c0 = (j0 < cr) ? scol[s0 + j0] : -1;   // broadcast within q-group
                int c1 = (j1 < cr) ? scol[s0 + j1] : -1;
                if (c0 >= 0) {
                    if (BF) {
                        uint4 d = *reinterpret_cast<const uint4*>(
                            feat_bf + (size_t)c0 * D_FEAT + sub * 8);
                        a0[0] += bf_lo(d.x); a0[1] += bf_hi(d.x);
                        a0[2] += bf_lo(d.y); a0[3] += bf_hi(d.y);
                        a0[4] += bf_lo(d.z); a0[5] += bf_hi(d.z);
                        a0[6] += bf_lo(d.w); a0[7] += bf_hi(d.w);
                    } else {
                        float4 x0 = *reinterpret_cast<const float4*>(feat + (size_t)c0 * D_FEAT + sub * 8);
                        float4 x1 = *reinterpret_cast<const float4*>(feat + (size_t)c0 * D_FEAT + sub * 8 + 4);
                        a0[0] += x0.x; a0[1] += x0.y; a0[2] += x0.z; a0[3] += x0.w;
                        a0[4] += x1.x; a0[5] += x1.y; a0[6] += x1.z; a0[7] += x1.w;
                    }
                }
                if (c1 >= 0) {
                    if (BF) {
                        uint4 d = *reinterpret_cast<const uint4*>(
                            feat_bf + (size_t)c1 * D_FEAT + sub * 8);
                        a1[0] += bf_lo(d.x); a1[1] += bf_hi(d.x);
                        a1[2] += bf_lo(d.y); a1[3] += bf_hi(d.y);
                        a1[4] += bf_lo(d.z); a1[5] += bf_hi(d.z);
                        a1[6] += bf_lo(d.w); a1[7] += bf_hi(d.w);
                    } else {
                        float4 x0 = *reinterpret_cast<const float4*>(feat + (size_t)c1 * D_FEAT + sub * 8);
                        float4 x1 = *reinterpret_cast<const float4*>(feat + (size_t)c1 * D_FEAT + sub * 8 + 4);
                        a1[0] += x0.x; a1[1] += x0.y; a1[2] += x0.z; a1[3] += x0.w;
                        a1[4] += x1.x; a1[5] += x1.y; a1[6] += x1.z; a1[7] += x1.w;
                    }
                }
            }
            #pragma unroll
            for (int k = 0; k < 8; ++k) a0[k] += a1[k];
            #pragma unroll
            for (int k = 0; k < 8; ++k) {
                a0[k] += __shfl_xor(a0[k], 8, 64);
                a0[k] += __shfl_xor(a0[k], 16, 64);
                a0[k] += __shfl_xor(a0[k], 32, 64);
            }
            if (qg == 0) {
                float* ap = accs + lr * D_FEAT + sub * 8;
                #pragma unroll
                for (int k = 0; k < 8; ++k) ap[k] += a0[k];
            }
        }
        // overflow side-list additions (block-uniform; ~never taken)
        if (total > CAP2) {
            __syncthreads();
            if (w == 0) {
                int noc = min(oc, OVCAP);
                for (int o0 = 0; o0 < noc; o0 += 64) {
                    int oi = o0 + lane;
                    int2 rc = (oi < noc) ? ovf[oi] : make_int2(-1, 0);
                    bool match = (rc.x >= 0) && ((rc.x >> 8) == B) && (((rc.x >> 6) & 3) == q);
                    unsigned long long mask = __ballot(match);
                    while (mask) {
                        int l = __ffsll(mask) - 1;
                        int rr = __shfl(rc.x, l, 64);
                        int cc = __shfl(rc.y, l, 64);
                        int lr = rr & 63;
                        if (lane < 8) {
                            float fv[8];
                            if (BF) {
                                uint4 d = *reinterpret_cast<const uint4*>(
                                    feat_bf + (size_t)cc * D_FEAT + lane * 8);
                                fv[0] = bf_lo(d.x); fv[1] = bf_hi(d.x);
                                fv[2] = bf_lo(d.y); fv[3] = bf_hi(d.y);
                                fv[4] = bf_lo(d.z); fv[5] = bf_hi(d.z);
                                fv[6] = bf_lo(d.w); fv[7] = bf_hi(d.w);
                            } else {
                                float4 x0 = *reinterpret_cast<const float4*>(feat + (size_t)cc * D_FEAT + lane * 8);
                                float4 x1 = *reinterpret_cast<const float4*>(feat + (size_t)cc * D_FEAT + lane * 8 + 4);
                                fv[0] = x0.x; fv[1] = x0.y; fv[2] = x0.z; fv[3] = x0.w;
                                fv[4] = x1.x; fv[5] = x1.y; fv[6] = x1.z; fv[7] = x1.w;
                            }
                            float* ap = accs + lr * D_FEAT + lane * 8;
                            #pragma unroll
                            for (int k = 0; k < 8; ++k) ap[k] += fv[k];
                        }
                        if (lane == 0) ddeg[lr] += 1;
                        mask &= mask - 1;
                    }
                }
            }
        }
    } else {
        // correctness-only fallback: wave 0 rescans the raw edge list
        if (t < RB) ddeg[t] = 0;
        __syncthreads();
        if (w == 0) {
            for (int e0 = 0; e0 < n_edges; e0 += 64) {
                int e = e0 + lane;
                int rr = (e < n_edges) ? row[e] : -1;
                int cc = (e < n_edges) ? col[e] : 0;
                bool match = (rr >= 0) && ((rr >> 8) == B) && (((rr >> 6) & 3) == q);
                unsigned long long mask = __ballot(match);
                while (mask) {
                    int l = __ffsll(mask) - 1;
                    int r2 = __shfl(rr, l, 64);
                    int c2 = __shfl(cc, l, 64);
                    int lr = r2 & 63;
                    if (lane < 8) {
                        float fv[8];
                        if (BF) {
                            uint4 d = *reinterpret_cast<const uint4*>(
                                feat_bf + (size_t)c2 * D_FEAT + lane * 8);
                            fv[0] = bf_lo(d.x); fv[1] = bf_hi(d.x);
                            fv[2] = bf_lo(d.y); fv[3] = bf_hi(d.y);
                            fv[4] = bf_lo(d.z); fv[5] = bf_hi(d.z);
                            fv[6] = bf_lo(d.w); fv[7] = bf_hi(d.w);
                        } else {
                            float4 x0 = *reinterpret_cast<const float4*>(feat + (size_t)c2 * D_FEAT + lane * 8);
                            float4 x1 = *reinterpret_cast<const float4*>(feat + (size_t)c2 * D_FEAT + lane * 8 + 4);
                            fv[0] = x0.x; fv[1] = x0.y; fv[2] = x0.z; fv[3] = x0.w;
                            fv[4] = x1.x; fv[5] = x1.y; fv[6] = x1.z; fv[7] = x1.w;
                        }
                        float* ap = accs + lr * D_FEAT + lane * 8;
                        #pragma unroll
                        for (int k = 0; k < 8; ++k) ap[k] += fv[k];
                    }
                    if (lane == 0) ddeg[lr] += 1;
                    mask &= mask - 1;
                }
            }
        }
    }
    __syncthreads();

    // epilogue: out[r] = feat[r] + acc[r]/max(deg,1); fully coalesced
    int r0 = blk * RB;
    for (int j = t; j < RB * (D_FEAT / 4); j += 256) {
        int lr = j >> 4;
        int r = r0 + lr;
        if (r >= n_nodes) break;   // rows increase with j for fixed t
        int f = (j & 15) * 4;
        float inv = 1.0f / fmaxf((float)ddeg[lr], 1.0f);
        const float* ap = accs + lr * D_FEAT + f;
        size_t off = (size_t)r * D_FEAT + f;
        float4 fv = *reinterpret_cast<const float4*>(feat + off);
        float4 o;
        o.x = fv.x + ap[0] * inv;
        o.y = fv.y + ap[1] * inv;
        o.z = fv.z + ap[2] * inv;
        o.w = fv.w + ap[3] * inv;
        *reinterpret_cast<float4*>(out + off) = o;
    }
}

extern "C" void kernel_launch(void* const* d_in, const int* in_sizes, int n_in,
                              void* d_out, int out_size, void* d_ws, size_t ws_size,
                              hipStream_t stream) {
    const float* feat = (const float*)d_in[0];
    const int* row = (const int*)d_in[1];
    const int* col = (const int*)d_in[2];
    float* out = (float*)d_out;

    const int n_nodes = in_sizes[0] / D_FEAT;
    const int n_edges = in_sizes[1];
    const int nb2 = (n_nodes + CB - 1) / CB;              // 391
    const int ebt = (n_edges + E_BLK - 1) / E_BLK;        // 196
    const int n4 = n_nodes * D_FEAT / 4;                  // 1.6M float4s

    size_t slab_bytes = (size_t)nb2 * CAP2 * 4;           // 7.2 MB
    size_t cur_bytes  = ((size_t)nb2 * CURSTRIDE + 16) * 4; // ~25 KB (incl ovfcnt)
    size_t ovf_bytes  = (size_t)OVCAP * 8;                // 0.5 MB
    size_t bf_bytes   = (size_t)n_nodes * D_FEAT * 2;     // 12.8 MB

    size_t lean_need = slab_bytes + cur_bytes + ovf_bytes + 256;
    size_t fat_need  = lean_need + ((bf_bytes + 63) & ~(size_t)63);
    bool fat = (ws_size >= fat_need);

    char* ws = (char*)d_ws;
    size_t p = 0;
    int* slab = (int*)(ws + p); p += slab_bytes;
    int* gcur = (int*)(ws + p); p += cur_bytes;
    int2* ovf = (int2*)(ws + p); p += ovf_bytes;
    p = (p + 63) & ~(size_t)63;
    unsigned short* feat_bf = nullptr;
    if (fat) { feat_bf = (unsigned short*)(ws + p); }

    zero_kernel<<<32, 256, 0, stream>>>(gcur, nb2 * CURSTRIDE + 1);

    {
        int conv_blocks = fat ? (n4 + 255) / 256 : 0;
        part_conv_kernel<<<ebt + conv_blocks, 256, 0, stream>>>(
            row, col, gcur, slab, ovf, n_edges, ebt, nb2,
            feat, feat_bf, fat ? n4 : 0);
    }
    if (fat) {
        aggregate4_kernel<1><<<nb2 * 4, 256, 0, stream>>>(
            feat, feat_bf, slab, gcur, ovf, row, col, out, n_nodes, n_edges, nb2);
    } else {
        aggregate4_kernel<0><<<nb2 * 4, 256, 0, stream>>>(
            feat, nullptr, slab, gcur, ovf, row, col, out, n_nodes, n_edges, nb2);
    }
}

// Round 5
// 151.792 us; speedup vs baseline: 5.2961x; 1.2197x over previous
//
#include <hip/hip_runtime.h>

// N=100000 nodes, E=1600000 edges, D=64.
// Pipeline: zero(ovfcnt) -> bin2_conv (atomic-free cell binning + bf16 conv)
//           -> aggregate5 (per-64-row bucket: LDS counting sort + per-lane-group
//              register accumulation, direct coalesced write).
//
// Binning: each (tile, bucket) owns a PRIVATE 16-slot cell = one 64B line
// (single writer block -> no cross-XCD line sharing, no global atomics).
// cnts[tile][bucket] holds the raw per-cell count (coalesced row write).
#define D_FEAT 64
#define RB 64                 // rows per bucket -> nb = ceil(N/64) = 1563
#define RBITS 6
#define CELLCAP 16            // slots per (tile,bucket) cell = 64 B line
#define E_BLK 8192            // edges per binning tile -> ebt = 196
#define TMAX 256              // max tiles supported (E <= 2.09M)
#define NBMAX2 1600           // max buckets
#define SCAP 2048             // scol capacity (bucket mean 1024, sd 32 -> +32 sigma)
#define OVCAP 65536           // overflow side list (expected ~10 entries used)

__device__ inline unsigned short f2bf(float f) {
    unsigned u = __float_as_uint(f);
    u += 0x7FFFu + ((u >> 16) & 1u);   // RNE
    return (unsigned short)(u >> 16);
}
__device__ inline float bf_lo(unsigned u) { return __uint_as_float(u << 16); }
__device__ inline float bf_hi(unsigned u) { return __uint_as_float(u & 0xFFFF0000u); }

// ---------------- K0: zero the overflow counter ----------------------------
__global__ __launch_bounds__(64)
void zero_kernel(int* __restrict__ p, int n) {
    int i = blockIdx.x * 64 + threadIdx.x;
    if (i < n) p[i] = 0;
}

// ---------------- K1: atomic-free cell binning (+ bf16 conv) ---------------
__global__ __launch_bounds__(256)
void bin2_conv_kernel(const int* __restrict__ row, const int* __restrict__ col,
                      int* __restrict__ cnts,       // [ebt][nb] raw cell counts
                      int* __restrict__ slab,       // [nb][ebt][CELLCAP]
                      int* __restrict__ ovfcnt,     // 1 int, pre-zeroed
                      int2* __restrict__ ovf,       // [OVCAP]
                      int n_edges, int ebt, int nb,
                      const float* __restrict__ feat, unsigned short* __restrict__ feat_bf,
                      int n4) {
    int gb = blockIdx.x;
    int t = threadIdx.x;
    if (gb < ebt) {
        __shared__ int hist[NBMAX2];
        __shared__ int cur[NBMAX2];
        for (int i = t; i < nb; i += 256) { hist[i] = 0; cur[i] = 0; }
        __syncthreads();
        int e0 = gb * E_BLK, e1 = min(e0 + E_BLK, n_edges);
        for (int e = e0 + t; e < e1; e += 256)
            atomicAdd(&hist[row[e] >> RBITS], 1);
        __syncthreads();
        for (int i = t; i < nb; i += 256)
            cnts[(size_t)gb * nb + i] = hist[i];          // coalesced row write
        for (int e = e0 + t; e < e1; e += 256) {
            int r = row[e], c = col[e];
            int b = r >> RBITS;
            int pos = atomicAdd(&cur[b], 1);              // LDS atomic only
            if (pos < CELLCAP) {
                slab[((size_t)b * ebt + gb) * CELLCAP + pos] = ((r & (RB - 1)) << 17) | c;
            } else {
                int op = atomicAdd(ovfcnt, 1);            // ~10 total, negligible
                if (op < OVCAP) ovf[op] = make_int2(r, c);
            }
        }
    } else {
        int i = (gb - ebt) * 256 + t;
        if (i < n4) {
            float4 f = reinterpret_cast<const float4*>(feat)[i];
            ushort4 u;
            u.x = f2bf(f.x); u.y = f2bf(f.y); u.z = f2bf(f.z); u.w = f2bf(f.w);
            reinterpret_cast<ushort4*>(feat_bf)[i] = u;
        }
    }
}

// ---------------- K2: per-bucket sort + lane-group register aggregation ----
// Block b reads its contiguous cell strip slab[b][0..ebt*16), counting-sorts
// valid entries into scol, then each 8-lane group owns rows (w*16+q) and
// (w*16+q+8): 16 persistent accumulator VGPRs, no shfl fold, direct write.
template<int BF>
__global__ __launch_bounds__(256, 6)
void aggregate5_kernel(const float* __restrict__ feat,
                       const unsigned short* __restrict__ feat_bf,
                       const int* __restrict__ slab,
                       const int* __restrict__ cnts,
                       const int* __restrict__ ovfcnt,
                       const int2* __restrict__ ovf,
                       const int* __restrict__ row, const int* __restrict__ col,
                       float* __restrict__ out, int n_nodes, int n_edges,
                       int nb, int ebt) {
    __shared__ int cellc[TMAX];               // 1 KB
    __shared__ int scol[SCAP];                // 8 KB
    __shared__ int cnt[RB], csum[RB], cur[RB], ddeg[RB];
    __shared__ int sred[256];                 // 1 KB

    int b = blockIdx.x;
    int t = threadIdx.x;
    int w = t >> 6, lane = t & 63;
    int q = lane >> 3, sub = lane & 7;
    int rA = w * 16 + q;                      // this lane-group's two rows
    int rB = rA + 8;

    for (int i = t; i < ebt; i += 256) cellc[i] = cnts[(size_t)i * nb + b];
    if (t < RB) { cnt[t] = 0; ddeg[t] = 0; }
    __syncthreads();

    int pt = 0;
    for (int i = t; i < ebt; i += 256) pt += cellc[i];
    sred[t] = pt;
    __syncthreads();
    for (int o = 128; o > 0; o >>= 1) {
        if (t < o) sred[t] += sred[t + o];
        __syncthreads();
    }
    int btotal = sred[0];                     // raw edges destined for bucket b
    int rawoc = *ovfcnt;
    int oc = min(rawoc, OVCAP);
    bool fb = (btotal > SCAP) || (rawoc > OVCAP);

    float acc[16];
    #pragma unroll
    for (int k = 0; k < 16; ++k) acc[k] = 0.f;

#define GATHER(cv, o0)                                                         \
    do {                                                                       \
        if (BF) {                                                              \
            uint4 d = *reinterpret_cast<const uint4*>(                         \
                feat_bf + (size_t)(cv)*D_FEAT + sub * 8);                      \
            acc[o0+0] += bf_lo(d.x); acc[o0+1] += bf_hi(d.x);                  \
            acc[o0+2] += bf_lo(d.y); acc[o0+3] += bf_hi(d.y);                  \
            acc[o0+4] += bf_lo(d.z); acc[o0+5] += bf_hi(d.z);                  \
            acc[o0+6] += bf_lo(d.w); acc[o0+7] += bf_hi(d.w);                  \
        } else {                                                               \
            float4 x0 = *reinterpret_cast<const float4*>(                      \
                feat + (size_t)(cv)*D_FEAT + sub * 8);                         \
            float4 x1 = *reinterpret_cast<const float4*>(                      \
                feat + (size_t)(cv)*D_FEAT + sub * 8 + 4);                     \
            acc[o0+0] += x0.x; acc[o0+1] += x0.y;                              \
            acc[o0+2] += x0.z; acc[o0+3] += x0.w;                              \
            acc[o0+4] += x1.x; acc[o0+5] += x1.y;                              \
            acc[o0+6] += x1.z; acc[o0+7] += x1.w;                              \
        }                                                                      \
    } while (0)

    if (!fb) {
        int nslots = ebt * CELLCAP;
        const int* sp = slab + (size_t)b * nslots;
        // pass 1: count rows (valid slots only)
        for (int i = t; i < nslots; i += 256) {
            int cell = i >> 4, pos = i & 15;
            if (pos < min(cellc[cell], CELLCAP)) {
                int pk = sp[i];
                atomicAdd(&cnt[((unsigned)pk) >> 17], 1);
            }
        }
        for (int i = t; i < oc; i += 256) {
            int2 rc = ovf[i];
            if ((rc.x >> RBITS) == b) atomicAdd(&cnt[rc.x & (RB - 1)], 1);
        }
        __syncthreads();
        if (t < RB) csum[t] = cnt[t];
        __syncthreads();
        for (int o = 1; o < RB; o <<= 1) {
            int v = (t < RB && t >= o) ? csum[t - o] : 0;
            __syncthreads();
            if (t < RB) csum[t] += v;
            __syncthreads();
        }
        if (t < RB) { cur[t] = csum[t] - cnt[t]; ddeg[t] = cnt[t]; }
        __syncthreads();
        // pass 2: scatter cols row-grouped into scol (total = btotal <= SCAP)
        for (int i = t; i < nslots; i += 256) {
            int cell = i >> 4, pos = i & 15;
            if (pos < min(cellc[cell], CELLCAP)) {
                int pk = sp[i];
                int lr = ((unsigned)pk) >> 17;
                scol[atomicAdd(&cur[lr], 1)] = pk & 0x1FFFF;
            }
        }
        for (int i = t; i < oc; i += 256) {
            int2 rc = ovf[i];
            if ((rc.x >> RBITS) == b)
                scol[atomicAdd(&cur[rc.x & (RB - 1)], 1)] = rc.y;
        }
        __syncthreads();
        // gather: 8-lane group owns rows rA, rB exclusively
        int cA = cnt[rA], sA = csum[rA] - cA;
        int cB = cnt[rB], sB = csum[rB] - cB;
        int m = max(cA, cB);
        for (int j = 0; j < m; ++j) {
            if (j < cA) { int c = scol[sA + j]; GATHER(c, 0); }
            if (j < cB) { int c = scol[sB + j]; GATHER(c, 8); }
        }
    } else {
        // correctness-only fallback: chunked scan of the raw edge list
        for (int base = 0; base < n_edges; base += SCAP) {
            int ce = min(SCAP, n_edges - base);
            if (t < RB) cnt[t] = 0;
            __syncthreads();
            for (int i = t; i < ce; i += 256) {
                int r = row[base + i];
                if ((r >> RBITS) == b) atomicAdd(&cnt[r & (RB - 1)], 1);
            }
            __syncthreads();
            if (t < RB) csum[t] = cnt[t];
            __syncthreads();
            for (int o = 1; o < RB; o <<= 1) {
                int v = (t < RB && t >= o) ? csum[t - o] : 0;
                __syncthreads();
                if (t < RB) csum[t] += v;
                __syncthreads();
            }
            if (t < RB) { cur[t] = csum[t] - cnt[t]; ddeg[t] += cnt[t]; }
            __syncthreads();
            for (int i = t; i < ce; i += 256) {
                int r = row[base + i];
                if ((r >> RBITS) == b)
                    scol[atomicAdd(&cur[r & (RB - 1)], 1)] = col[base + i];
            }
            __syncthreads();
            int cA = cnt[rA], sA = csum[rA] - cA;
            int cB = cnt[rB], sB = csum[rB] - cB;
            int m = max(cA, cB);
            for (int j = 0; j < m; ++j) {
                if (j < cA) { int c = scol[sA + j]; GATHER(c, 0); }
                if (j < cB) { int c = scol[sB + j]; GATHER(c, 8); }
            }
            __syncthreads();   // scol/cnt reused next chunk
        }
    }
    __syncthreads();

    // epilogue: out[r] = feat[r] + acc[r]/max(deg,1); all 64 lanes write
    {
        int r = b * RB + rA;
        if (r < n_nodes) {
            float inv = 1.0f / fmaxf((float)ddeg[rA], 1.0f);
            size_t off = (size_t)r * D_FEAT + sub * 8;
            float4 f0 = *reinterpret_cast<const float4*>(feat + off);
            float4 f1 = *reinterpret_cast<const float4*>(feat + off + 4);
            float4 o0, o1;
            o0.x = f0.x + acc[0] * inv; o0.y = f0.y + acc[1] * inv;
            o0.z = f0.z + acc[2] * inv; o0.w = f0.w + acc[3] * inv;
            o1.x = f1.x + acc[4] * inv; o1.y = f1.y + acc[5] * inv;
            o1.z = f1.z + acc[6] * inv; o1.w = f1.w + acc[7] * inv;
            *reinterpret_cast<float4*>(out + off) = o0;
            *reinterpret_cast<float4*>(out + off + 4) = o1;
        }
        r = b * RB + rB;
        if (r < n_nodes) {
            float inv = 1.0f / fmaxf((float)ddeg[rB], 1.0f);
            size_t off = (size_t)r * D_FEAT + sub * 8;
            float4 f0 = *reinterpret_cast<const float4*>(feat + off);
            float4 f1 = *reinterpret_cast<const float4*>(feat + off + 4);
            float4 o0, o1;
            o0.x = f0.x + acc[8]  * inv; o0.y = f0.y + acc[9]  * inv;
            o0.z = f0.z + acc[10] * inv; o0.w = f0.w + acc[11] * inv;
            o1.x = f1.x + acc[12] * inv; o1.y = f1.y + acc[13] * inv;
            o1.z = f1.z + acc[14] * inv; o1.w = f1.w + acc[15] * inv;
            *reinterpret_cast<float4*>(out + off) = o0;
            *reinterpret_cast<float4*>(out + off + 4) = o1;
        }
    }
#undef GATHER
}

extern "C" void kernel_launch(void* const* d_in, const int* in_sizes, int n_in,
                              void* d_out, int out_size, void* d_ws, size_t ws_size,
                              hipStream_t stream) {
    const float* feat = (const float*)d_in[0];
    const int* row = (const int*)d_in[1];
    const int* col = (const int*)d_in[2];
    float* out = (float*)d_out;

    const int n_nodes = in_sizes[0] / D_FEAT;
    const int n_edges = in_sizes[1];
    const int nb = (n_nodes + RB - 1) / RB;               // 1563
    const int ebt = (n_edges + E_BLK - 1) / E_BLK;        // 196  (<= TMAX)
    const int n4 = n_nodes * D_FEAT / 4;                  // 1.6M float4s

    size_t slab_bytes = (size_t)nb * ebt * CELLCAP * 4;   // 19.6 MB
    size_t cnts_bytes = (size_t)ebt * nb * 4;             // 1.2 MB
    size_t ovf_bytes  = (size_t)OVCAP * 8;                // 0.5 MB
    size_t bf_bytes   = (size_t)n_nodes * D_FEAT * 2;     // 12.8 MB

    size_t lean_need = slab_bytes + cnts_bytes + ovf_bytes + 512;
    size_t fat_need  = lean_need + ((bf_bytes + 63) & ~(size_t)63);
    bool fat = (ws_size >= fat_need);

    char* ws = (char*)d_ws;
    size_t p = 0;
    int* slab = (int*)(ws + p); p += slab_bytes;          // 64B-aligned cells
    int* cnts = (int*)(ws + p); p += cnts_bytes;
    int2* ovf = (int2*)(ws + p); p += ovf_bytes;
    int* ovfcnt = (int*)(ws + p); p += 64;
    p = (p + 63) & ~(size_t)63;
    unsigned short* feat_bf = nullptr;
    if (fat) { feat_bf = (unsigned short*)(ws + p); }

    zero_kernel<<<1, 64, 0, stream>>>(ovfcnt, 1);

    {
        int conv_blocks = fat ? (n4 + 255) / 256 : 0;
        bin2_conv_kernel<<<ebt + conv_blocks, 256, 0, stream>>>(
            row, col, cnts, slab, ovfcnt, ovf, n_edges, ebt, nb,
            feat, feat_bf, fat ? n4 : 0);
    }
    if (fat) {
        aggregate5_kernel<1><<<nb, 256, 0, stream>>>(
            feat, feat_bf, slab, cnts, ovfcnt, ovf, row, col,
            out, n_nodes, n_edges, nb, ebt);
    } else {
        aggregate5_kernel<0><<<nb, 256, 0, stream>>>(
            feat, nullptr, slab, cnts, ovfcnt, ovf, row, col,
            out, n_nodes, n_edges, nb, ebt);
    }
}